// Round 2
// baseline (284.957 us; speedup 1.0000x reference)
//
#include <hip/hip_runtime.h>

#define B_ 4
#define T_ 1024
#define D_ 1024
#define H_ 16
#define HD_ 64

typedef unsigned short u16;
typedef __bf16 bf16x8 __attribute__((ext_vector_type(8)));
typedef float f32x4 __attribute__((ext_vector_type(4)));
typedef unsigned short u16x4 __attribute__((ext_vector_type(4)));

__device__ inline u16 f2b(float f) {
    union { float f; unsigned u; } v; v.f = f;
    unsigned r = v.u + 0x7fffu + ((v.u >> 16) & 1u);
    return (u16)(r >> 16);
}

__device__ inline f32x4 mfma16(bf16x8 a, bf16x8 b, f32x4 c) {
    return __builtin_amdgcn_mfma_f32_16x16x32_bf16(a, b, c, 0, 0, 0);
}

// ---------------- sequence lengths from mask (dtype-agnostic) ----------------
// sequence_mask is a prefix mask (arange < length). Element size is unknown
// (bool->uint8 vs int32 vs fp32 depending on harness). Detect: byte[1]==0 means
// 4-byte elements (mask[0][1] is true for length>=2, so a 1-byte encoding has
// byte[1]!=0). Then length = count of nonzero elements in the row.
__global__ __launch_bounds__(256) void len_kernel(const unsigned char* __restrict__ m,
                                                  int* __restrict__ lens) {
    const int t = threadIdx.x;
    const int b = blockIdx.x;
    const int esz4 = (m[1] == 0);
    int c = 0;
    for (int i = t; i < T_; i += 256) {
        bool v = esz4 ? (((const int*)m)[b * T_ + i] != 0) : (m[b * T_ + i] != 0);
        c += v ? 1 : 0;
    }
#pragma unroll
    for (int off = 1; off < 64; off <<= 1) c += __shfl_xor(c, off);
    __shared__ int red[4];
    if ((t & 63) == 0) red[t >> 6] = c;
    __syncthreads();
    if (t == 0) lens[b] = red[0] + red[1] + red[2] + red[3];
}

// ---------------- fp32 -> bf16 conversion (weights) ----------------
__global__ __launch_bounds__(256) void cvt_bf16(const float* __restrict__ in,
                                                u16* __restrict__ out, int n4) {
    int i = blockIdx.x * 256 + threadIdx.x;
    int stride = gridDim.x * 256;
    for (; i < n4; i += stride) {
        float4 v = ((const float4*)in)[i];
        u16x4 o = { f2b(v.x), f2b(v.y), f2b(v.z), f2b(v.w) };
        ((u16x4*)out)[i] = o;
    }
}

// ---------------- LayerNorm -> bf16 x ----------------
__global__ __launch_bounds__(256) void ln_kernel(const float* __restrict__ x,
                                                 const float* __restrict__ g,
                                                 const float* __restrict__ be,
                                                 u16* __restrict__ y) {
    __shared__ float red[8];
    const int row = blockIdx.x;
    const int tid = threadIdx.x;
    const float* xr = x + (size_t)row * D_;
    float4 v = ((const float4*)xr)[tid];
    float s  = v.x + v.y + v.z + v.w;
    float ss = v.x*v.x + v.y*v.y + v.z*v.z + v.w*v.w;
#pragma unroll
    for (int off = 1; off < 64; off <<= 1) {
        s  += __shfl_xor(s, off);
        ss += __shfl_xor(ss, off);
    }
    const int w = tid >> 6;
    if ((tid & 63) == 0) { red[w*2] = s; red[w*2+1] = ss; }
    __syncthreads();
    s  = red[0] + red[2] + red[4] + red[6];
    ss = red[1] + red[3] + red[5] + red[7];
    const float mu = s * (1.f/1024.f);
    const float rs = rsqrtf(ss*(1.f/1024.f) - mu*mu + 1e-5f);
    float4 gv = ((const float4*)g)[tid];
    float4 bv = ((const float4*)be)[tid];
    u16x4 o = { f2b((v.x-mu)*rs*gv.x + bv.x),
                f2b((v.y-mu)*rs*gv.y + bv.y),
                f2b((v.z-mu)*rs*gv.z + bv.z),
                f2b((v.w-mu)*rs*gv.w + bv.w) };
    ((u16x4*)(y + (size_t)row * D_))[tid] = o;
}

// ---------------- GEMM C = A @ B^T (+bias), A:MxK, B:NxK, bf16 ----------------
// EPI 0: write fp32 C (out projection, straight into d_out)
// EPI 1: QKV epilogue -> scatter bf16 into Q[b][h][t][d] (x0.125), K[b][h][t][d], Vt[b][h][d][t]
template <int EPI>
__global__ __launch_bounds__(256) void gemm_bt(
    const u16* __restrict__ A, const u16* __restrict__ Bw,
    const float* __restrict__ bias, float* __restrict__ Cf,
    u16* __restrict__ Qb, u16* __restrict__ Kb, u16* __restrict__ Vt,
    int M, int N, int K) {
    __shared__ u16 As[128 * 64];
    __shared__ u16 Bs[128 * 64];
    const int tid = threadIdx.x;
    const int w = tid >> 6, l = tid & 63;
    const int l15 = l & 15, lg = l >> 4;
    const int m0 = blockIdx.y * 128, n0 = blockIdx.x * 128;
    const int wr = w >> 1, wc = w & 1;
    const int ldr = l >> 3;          // row within 8-row chunk
    const int ldc = (l & 7) * 8;     // bf16 column

    f32x4 acc[4][4];
#pragma unroll
    for (int m = 0; m < 4; m++)
#pragma unroll
        for (int n = 0; n < 4; n++) acc[m][n] = (f32x4){0.f, 0.f, 0.f, 0.f};

    for (int k0 = 0; k0 < K; k0 += 64) {
#pragma unroll
        for (int it = 0; it < 4; ++it) {
            const int c = it * 4 + w;
            const u16* ga = A  + (size_t)(m0 + c*8 + ldr) * K + (k0 + ldc);
            const u16* gb = Bw + (size_t)(n0 + c*8 + ldr) * K + (k0 + ldc);
            __builtin_amdgcn_global_load_lds(
                (const __attribute__((address_space(1))) unsigned int*)ga,
                (__attribute__((address_space(3))) unsigned int*)(As + c * 512), 16, 0, 0);
            __builtin_amdgcn_global_load_lds(
                (const __attribute__((address_space(1))) unsigned int*)gb,
                (__attribute__((address_space(3))) unsigned int*)(Bs + c * 512), 16, 0, 0);
        }
        __syncthreads();
#pragma unroll
        for (int kk = 0; kk < 64; kk += 32) {
            bf16x8 af[4], bfr[4];
#pragma unroll
            for (int m = 0; m < 4; m++)
                af[m] = *(const bf16x8*)&As[(wr*64 + m*16 + l15) * 64 + kk + lg*8];
#pragma unroll
            for (int n = 0; n < 4; n++)
                bfr[n] = *(const bf16x8*)&Bs[(wc*64 + n*16 + l15) * 64 + kk + lg*8];
#pragma unroll
            for (int m = 0; m < 4; m++)
#pragma unroll
                for (int n = 0; n < 4; n++)
                    acc[m][n] = mfma16(af[m], bfr[n], acc[m][n]);
        }
        __syncthreads();
    }

#pragma unroll
    for (int m = 0; m < 4; m++) {
#pragma unroll
        for (int n = 0; n < 4; n++) {
            const int col = n0 + wc*64 + n*16 + l15;
            const float bv = bias[col];
            if constexpr (EPI == 0) {
#pragma unroll
                for (int r = 0; r < 4; r++) {
                    const int row = m0 + wr*64 + m*16 + lg*4 + r;
                    Cf[(size_t)row * N + col] = acc[m][n][r] + bv;
                }
            } else {
                const int which = col >> 10;
                const int d = col & 1023;
                const int h = d >> 6, hd = d & 63;
#pragma unroll
                for (int r = 0; r < 4; r++) {
                    const int row = m0 + wr*64 + m*16 + lg*4 + r;
                    const int bb = row >> 10, t = row & 1023;
                    const float v = acc[m][n][r] + bv;
                    const size_t bh = (size_t)bb * H_ + h;
                    if (which == 0)      Qb[(bh * T_ + t) * HD_ + hd] = f2b(v * 0.125f);
                    else if (which == 1) Kb[(bh * T_ + t) * HD_ + hd] = f2b(v);
                    else                 Vt[(bh * HD_ + hd) * T_ + t] = f2b(v);
                }
            }
        }
    }
}

// ---------------- Flash attention, both mask variants ----------------
// grid: (T/64, B*H, 2). 4 waves/block, each wave owns a 16-row q strip.
__global__ __launch_bounds__(256) void attn_kernel(
    const u16* __restrict__ Qb, const u16* __restrict__ Kb,
    const u16* __restrict__ Vt, const int* __restrict__ lens,
    u16* __restrict__ Ob) {
    __shared__ u16 Pl[4][16 * 64];
    const int qt  = blockIdx.x;
    const int bh  = blockIdx.y;
    const int var = blockIdx.z;      // 0: causal+keypad, 1: keypad
    const int b = bh >> 4, h = bh & 15;
    const int tid = threadIdx.x, w = tid >> 6, l = tid & 63;
    const int l15 = l & 15, lg = l >> 4;
    const int len = lens[b];

    const u16* Qh = Qb + (size_t)bh * (T_ * HD_);
    const u16* Kh = Kb + (size_t)bh * (T_ * HD_);
    const u16* Vh = Vt + (size_t)bh * (HD_ * T_);

    const int q0 = qt * 64 + w * 16;

    const bf16x8 qf0 = *(const bf16x8*)(Qh + (size_t)(q0 + l15) * HD_ + lg * 8);
    const bf16x8 qf1 = *(const bf16x8*)(Qh + (size_t)(q0 + l15) * HD_ + 32 + lg * 8);

    f32x4 acc_o[4];
#pragma unroll
    for (int n = 0; n < 4; n++) acc_o[n] = (f32x4){0.f, 0.f, 0.f, 0.f};
    float m_r[4] = {-1e30f, -1e30f, -1e30f, -1e30f};
    float l_r[4] = {0.f, 0.f, 0.f, 0.f};

    const int nt_kv = (len + 63) >> 6;                       // tiles with any valid key
    const int nt = (var == 0) ? min(qt + 1, nt_kv) : nt_kv;
    u16* Pw = &Pl[w][0];

    for (int kt = 0; kt < nt; ++kt) {
        const int k0 = kt * 64;
        f32x4 s[4];
#pragma unroll
        for (int n = 0; n < 4; n++) {
            const u16* kr = Kh + (size_t)(k0 + n*16 + l15) * HD_ + lg * 8;
            bf16x8 kf0 = *(const bf16x8*)kr;
            bf16x8 kf1 = *(const bf16x8*)(kr + 32);
            f32x4 z = (f32x4){0.f, 0.f, 0.f, 0.f};
            z = mfma16(qf0, kf0, z);
            z = mfma16(qf1, kf1, z);
            s[n] = z;
        }
        float kpm[4];
        int kcol[4];
#pragma unroll
        for (int n = 0; n < 4; n++) {
            kcol[n] = k0 + n*16 + l15;
            kpm[n] = (kcol[n] < len) ? 0.f : -1e30f;
        }
#pragma unroll
        for (int r = 0; r < 4; r++) {
            const int qrow = q0 + lg*4 + r;
            float mx = -1e30f;
#pragma unroll
            for (int n = 0; n < 4; n++) {
                float vsm = s[n][r] + kpm[n];
                if (var == 0 && qrow < kcol[n]) vsm = -1e30f;
                s[n][r] = vsm;
                mx = fmaxf(mx, vsm);
            }
#pragma unroll
            for (int off = 1; off < 16; off <<= 1) mx = fmaxf(mx, __shfl_xor(mx, off));
            const float mnew = fmaxf(m_r[r], mx);
            const float fac = __expf(m_r[r] - mnew);
            m_r[r] = mnew;
            float ps = 0.f;
#pragma unroll
            for (int n = 0; n < 4; n++) {
                const float p = __expf(s[n][r] - mnew);
                s[n][r] = p;
                ps += p;
            }
#pragma unroll
            for (int off = 1; off < 16; off <<= 1) ps += __shfl_xor(ps, off);
            l_r[r] = l_r[r] * fac + ps;
#pragma unroll
            for (int n = 0; n < 4; n++) acc_o[n][r] *= fac;
        }
        // P (D-layout) -> LDS -> A-layout fragments (wave-private region, no barrier)
#pragma unroll
        for (int r = 0; r < 4; r++)
#pragma unroll
            for (int n = 0; n < 4; n++)
                Pw[(lg*4 + r) * 64 + n*16 + l15] = f2b(s[n][r]);
#pragma unroll
        for (int kk = 0; kk < 2; ++kk) {
            bf16x8 pa = *(const bf16x8*)&Pw[l15 * 64 + kk*32 + lg*8];
#pragma unroll
            for (int n = 0; n < 4; n++) {
                bf16x8 vb = *(const bf16x8*)(Vh + (size_t)(n*16 + l15) * T_ + k0 + kk*32 + lg*8);
                acc_o[n] = mfma16(pa, vb, acc_o[n]);
            }
        }
    }
    float inv[4];
#pragma unroll
    for (int r = 0; r < 4; r++) inv[r] = 1.f / l_r[r];
#pragma unroll
    for (int n = 0; n < 4; n++) {
#pragma unroll
        for (int r = 0; r < 4; r++) {
            const int row = q0 + lg*4 + r;
            const int dcol = n*16 + l15;
            Ob[((size_t)(var * B_ + b) * T_ + row) * D_ + h * HD_ + dcol] =
                f2b(acc_o[n][r] * inv[r]);
        }
    }
}

extern "C" void kernel_launch(void* const* d_in, const int* in_sizes, int n_in,
                              void* d_out, int out_size, void* d_ws, size_t ws_size,
                              hipStream_t stream) {
    const float* x_in   = (const float*)d_in[0];
    const float* gamma  = (const float*)d_in[1];
    const float* beta   = (const float*)d_in[2];
    const float* wqkv_f = (const float*)d_in[3];
    const float* bqkv   = (const float*)d_in[4];
    const float* wout_f = (const float*)d_in[5];
    const float* bout   = (const float*)d_in[6];
    const unsigned char* smask = (const unsigned char*)d_in[7];
    float* out = (float*)d_out;

    char* ws = (char*)d_ws;
    u16* xb   = (u16*)(ws);                        // 8 MB  LN output, bf16 [4096][1024]
    u16* wqkv = (u16*)(ws + ((size_t)8  << 20));   // 6 MB  in_proj_w bf16
    u16* wo   = (u16*)(ws + ((size_t)14 << 20));   // 2 MB  out_w bf16
    u16* Qb   = (u16*)(ws + ((size_t)16 << 20));   // 8 MB  Q [b][h][t][d] (pre-scaled)
    u16* Kb   = (u16*)(ws + ((size_t)24 << 20));   // 8 MB  K [b][h][t][d]
    u16* Vt   = (u16*)(ws + ((size_t)32 << 20));   // 8 MB  V^T [b][h][d][t]
    u16* Ob   = (u16*)(ws + ((size_t)40 << 20));   // 16 MB O [2*4096][1024] bf16
    int* lens = (int*)(ws + ((size_t)56 << 20));   // 16 B  per-batch lengths

    len_kernel<<<dim3(B_), dim3(256), 0, stream>>>(smask, lens);
    cvt_bf16<<<dim3(1024), dim3(256), 0, stream>>>(wqkv_f, wqkv, (3 * D_ * D_) / 4);
    cvt_bf16<<<dim3(512),  dim3(256), 0, stream>>>(wout_f, wo, (D_ * D_) / 4);
    ln_kernel<<<dim3(B_ * T_), dim3(256), 0, stream>>>(x_in, gamma, beta, xb);
    gemm_bt<1><<<dim3(24, 32), dim3(256), 0, stream>>>(
        xb, wqkv, bqkv, nullptr, Qb, Kb, Vt, B_ * T_, 3 * D_, D_);
    attn_kernel<<<dim3(T_ / 64, B_ * H_, 2), dim3(256), 0, stream>>>(Qb, Kb, Vt, lens, Ob);
    gemm_bt<0><<<dim3(8, 64), dim3(256), 0, stream>>>(
        Ob, wo, bout, out, nullptr, nullptr, nullptr, 2 * B_ * T_, D_, D_);
}

// Round 3
// 276.068 us; speedup vs baseline: 1.0322x; 1.0322x over previous
//
#include <hip/hip_runtime.h>

#define B_ 4
#define T_ 1024
#define D_ 1024
#define H_ 16
#define HD_ 64

typedef unsigned short u16;
typedef __bf16 bf16x8 __attribute__((ext_vector_type(8)));
typedef float f32x4 __attribute__((ext_vector_type(4)));
typedef unsigned short u16x4 __attribute__((ext_vector_type(4)));

__device__ inline u16 f2b(float f) {
    union { float f; unsigned u; } v; v.f = f;
    unsigned r = v.u + 0x7fffu + ((v.u >> 16) & 1u);
    return (u16)(r >> 16);
}

__device__ inline f32x4 mfma16(bf16x8 a, bf16x8 b, f32x4 c) {
    return __builtin_amdgcn_mfma_f32_16x16x32_bf16(a, b, c, 0, 0, 0);
}

// ---------------- sequence lengths from mask (dtype-agnostic) ----------------
__global__ __launch_bounds__(256) void len_kernel(const unsigned char* __restrict__ m,
                                                  int* __restrict__ lens) {
    const int t = threadIdx.x;
    const int b = blockIdx.x;
    const int esz4 = (m[1] == 0);
    int c = 0;
    for (int i = t; i < T_; i += 256) {
        bool v = esz4 ? (((const int*)m)[b * T_ + i] != 0) : (m[b * T_ + i] != 0);
        c += v ? 1 : 0;
    }
#pragma unroll
    for (int off = 1; off < 64; off <<= 1) c += __shfl_xor(c, off);
    __shared__ int red[4];
    if ((t & 63) == 0) red[t >> 6] = c;
    __syncthreads();
    if (t == 0) lens[b] = red[0] + red[1] + red[2] + red[3];
}

// ---------------- fp32 -> bf16 conversion (weights) ----------------
__global__ __launch_bounds__(256) void cvt_bf16(const float* __restrict__ in,
                                                u16* __restrict__ out, int n4) {
    int i = blockIdx.x * 256 + threadIdx.x;
    int stride = gridDim.x * 256;
    for (; i < n4; i += stride) {
        float4 v = ((const float4*)in)[i];
        u16x4 o = { f2b(v.x), f2b(v.y), f2b(v.z), f2b(v.w) };
        ((u16x4*)out)[i] = o;
    }
}

// ---------------- LayerNorm -> bf16 x ----------------
__global__ __launch_bounds__(256) void ln_kernel(const float* __restrict__ x,
                                                 const float* __restrict__ g,
                                                 const float* __restrict__ be,
                                                 u16* __restrict__ y) {
    __shared__ float red[8];
    const int row = blockIdx.x;
    const int tid = threadIdx.x;
    const float* xr = x + (size_t)row * D_;
    float4 v = ((const float4*)xr)[tid];
    float s  = v.x + v.y + v.z + v.w;
    float ss = v.x*v.x + v.y*v.y + v.z*v.z + v.w*v.w;
#pragma unroll
    for (int off = 1; off < 64; off <<= 1) {
        s  += __shfl_xor(s, off);
        ss += __shfl_xor(ss, off);
    }
    const int w = tid >> 6;
    if ((tid & 63) == 0) { red[w*2] = s; red[w*2+1] = ss; }
    __syncthreads();
    s  = red[0] + red[2] + red[4] + red[6];
    ss = red[1] + red[3] + red[5] + red[7];
    const float mu = s * (1.f/1024.f);
    const float rs = rsqrtf(ss*(1.f/1024.f) - mu*mu + 1e-5f);
    float4 gv = ((const float4*)g)[tid];
    float4 bv = ((const float4*)be)[tid];
    u16x4 o = { f2b((v.x-mu)*rs*gv.x + bv.x),
                f2b((v.y-mu)*rs*gv.y + bv.y),
                f2b((v.z-mu)*rs*gv.z + bv.z),
                f2b((v.w-mu)*rs*gv.w + bv.w) };
    ((u16x4*)(y + (size_t)row * D_))[tid] = o;
}

// ---------------- GEMM C = A @ B^T (+bias), A:MxK, B:NxK, bf16 ----------------
template <int EPI>
__global__ __launch_bounds__(256) void gemm_bt(
    const u16* __restrict__ A, const u16* __restrict__ Bw,
    const float* __restrict__ bias, float* __restrict__ Cf,
    u16* __restrict__ Qb, u16* __restrict__ Kb, u16* __restrict__ Vt,
    int M, int N, int K) {
    __shared__ u16 As[128 * 64];
    __shared__ u16 Bs[128 * 64];
    const int tid = threadIdx.x;
    const int w = tid >> 6, l = tid & 63;
    const int l15 = l & 15, lg = l >> 4;
    const int m0 = blockIdx.y * 128, n0 = blockIdx.x * 128;
    const int wr = w >> 1, wc = w & 1;
    const int ldr = l >> 3;          // row within 8-row chunk
    const int ldc = (l & 7) * 8;     // bf16 column

    f32x4 acc[4][4];
#pragma unroll
    for (int m = 0; m < 4; m++)
#pragma unroll
        for (int n = 0; n < 4; n++) acc[m][n] = (f32x4){0.f, 0.f, 0.f, 0.f};

    for (int k0 = 0; k0 < K; k0 += 64) {
#pragma unroll
        for (int it = 0; it < 4; ++it) {
            const int c = it * 4 + w;
            const u16* ga = A  + (size_t)(m0 + c*8 + ldr) * K + (k0 + ldc);
            const u16* gb = Bw + (size_t)(n0 + c*8 + ldr) * K + (k0 + ldc);
            __builtin_amdgcn_global_load_lds(
                (const __attribute__((address_space(1))) unsigned int*)ga,
                (__attribute__((address_space(3))) unsigned int*)(As + c * 512), 16, 0, 0);
            __builtin_amdgcn_global_load_lds(
                (const __attribute__((address_space(1))) unsigned int*)gb,
                (__attribute__((address_space(3))) unsigned int*)(Bs + c * 512), 16, 0, 0);
        }
        __syncthreads();
#pragma unroll
        for (int kk = 0; kk < 64; kk += 32) {
            bf16x8 af[4], bfr[4];
#pragma unroll
            for (int m = 0; m < 4; m++)
                af[m] = *(const bf16x8*)&As[(wr*64 + m*16 + l15) * 64 + kk + lg*8];
#pragma unroll
            for (int n = 0; n < 4; n++)
                bfr[n] = *(const bf16x8*)&Bs[(wc*64 + n*16 + l15) * 64 + kk + lg*8];
#pragma unroll
            for (int m = 0; m < 4; m++)
#pragma unroll
                for (int n = 0; n < 4; n++)
                    acc[m][n] = mfma16(af[m], bfr[n], acc[m][n]);
        }
        __syncthreads();
    }

#pragma unroll
    for (int m = 0; m < 4; m++) {
#pragma unroll
        for (int n = 0; n < 4; n++) {
            const int col = n0 + wc*64 + n*16 + l15;
            const float bv = bias[col];
            if constexpr (EPI == 0) {
#pragma unroll
                for (int r = 0; r < 4; r++) {
                    const int row = m0 + wr*64 + m*16 + lg*4 + r;
                    Cf[(size_t)row * N + col] = acc[m][n][r] + bv;
                }
            } else {
                const int which = col >> 10;
                const int d = col & 1023;
                const int h = d >> 6, hd = d & 63;
#pragma unroll
                for (int r = 0; r < 4; r++) {
                    const int row = m0 + wr*64 + m*16 + lg*4 + r;
                    const int bb = row >> 10, t = row & 1023;
                    const float v = acc[m][n][r] + bv;
                    const size_t bh = (size_t)bb * H_ + h;
                    if (which == 0)      Qb[(bh * T_ + t) * HD_ + hd] = f2b(v * 0.125f);
                    else if (which == 1) Kb[(bh * T_ + t) * HD_ + hd] = f2b(v);
                    else                 Vt[(bh * HD_ + hd) * T_ + t] = f2b(v);
                }
            }
        }
    }
}

// ---------------- Flash attention, swapped-operand form ----------------
// grid: (T/64, B*H, 2). 4 waves/block, each wave owns a 16-row q strip.
// QK^T computed as mfma(K,Q) -> S^T[k][q]: each lane owns ONE q (l15) and 16
// in-register k values -> softmax reduce = in-lane tree + 2 shfl_xor.
// PV computed as mfma(V,P) -> O^T[d][q]: rescale/normalize lane-local.
__global__ __launch_bounds__(256) void attn_kernel(
    const u16* __restrict__ Qb, const u16* __restrict__ Kb,
    const u16* __restrict__ Vt, const int* __restrict__ lens,
    u16* __restrict__ Ob) {
    __shared__ char Pl[4][16 * 64 * 2];   // per-wave P[q][k] bf16, XOR-swizzled
    const int qt  = blockIdx.x;
    const int bh  = blockIdx.y;
    const int var = blockIdx.z;      // 0: causal+keypad, 1: keypad
    const int b = bh >> 4, h = bh & 15;
    const int tid = threadIdx.x, w = tid >> 6, l = tid & 63;
    const int l15 = l & 15, lg = l >> 4;
    const int len = lens[b];

    const u16* Qh = Qb + (size_t)bh * (T_ * HD_);
    const u16* Kh = Kb + (size_t)bh * (T_ * HD_);
    const u16* Vh = Vt + (size_t)bh * (HD_ * T_);

    const int q0 = qt * 64 + w * 16;
    const int qrow = q0 + l15;              // this lane's q row

    const bf16x8 qf0 = *(const bf16x8*)(Qh + (size_t)qrow * HD_ + lg * 8);
    const bf16x8 qf1 = *(const bf16x8*)(Qh + (size_t)qrow * HD_ + 32 + lg * 8);

    f32x4 acc_o[4];                          // O^T[d = n*16+lg*4+r][q = l15]
#pragma unroll
    for (int n = 0; n < 4; n++) acc_o[n] = (f32x4){0.f, 0.f, 0.f, 0.f};
    float m_r = -1e30f, l_r = 0.f;           // per-lane (per-q) softmax state

    const int nt_kv = (len + 63) >> 6;
    const int nt = (var == 0) ? min(qt + 1, nt_kv) : nt_kv;

    char* Pw = &Pl[w][0];
    const int swz = (l15 & 7) << 4;          // XOR byte-swizzle within 128B row

    for (int kt = 0; kt < nt; ++kt) {
        const int k0 = kt * 64;
        f32x4 s[4];
#pragma unroll
        for (int n = 0; n < 4; n++) {
            const u16* kr = Kh + (size_t)(k0 + n*16 + l15) * HD_ + lg * 8;
            bf16x8 kf0 = *(const bf16x8*)kr;
            bf16x8 kf1 = *(const bf16x8*)(kr + 32);
            f32x4 z = (f32x4){0.f, 0.f, 0.f, 0.f};
            z = mfma16(kf0, qf0, z);         // S^T[k][q]
            z = mfma16(kf1, qf1, z);
            s[n] = z;
        }
        // mask (fully lane-local) + in-lane max tree
        float mxn[4];
#pragma unroll
        for (int n = 0; n < 4; n++) {
            const int kb = k0 + n*16 + lg*4;
            float v0, v1, v2, v3;
#pragma unroll
            for (int r = 0; r < 4; r++) {
                const int k = kb + r;
                const bool ok = (k < len) && (var == 1 || qrow >= k);
                const float v = ok ? s[n][r] : -1e30f;
                s[n][r] = v;
                (r == 0 ? v0 : r == 1 ? v1 : r == 2 ? v2 : v3) = v;
            }
            mxn[n] = fmaxf(fmaxf(v0, v1), fmaxf(v2, v3));
        }
        float mx = fmaxf(fmaxf(mxn[0], mxn[1]), fmaxf(mxn[2], mxn[3]));
        mx = fmaxf(mx, __shfl_xor(mx, 16));
        mx = fmaxf(mx, __shfl_xor(mx, 32));

        const float mnew = fmaxf(m_r, mx);
        const float fac = __expf(m_r - mnew);
        m_r = mnew;
        // exp + in-lane sum tree
        float pn[4];
#pragma unroll
        for (int n = 0; n < 4; n++) {
            float e0 = __expf(s[n][0] - mnew);
            float e1 = __expf(s[n][1] - mnew);
            float e2 = __expf(s[n][2] - mnew);
            float e3 = __expf(s[n][3] - mnew);
            s[n][0] = e0; s[n][1] = e1; s[n][2] = e2; s[n][3] = e3;
            pn[n] = (e0 + e1) + (e2 + e3);
        }
        float ps = (pn[0] + pn[1]) + (pn[2] + pn[3]);
        ps += __shfl_xor(ps, 16);
        ps += __shfl_xor(ps, 32);
        l_r = l_r * fac + ps;

        // rescale O (lane-local!) and pack P -> LDS (swizzled, 4 k-contig per write)
#pragma unroll
        for (int n = 0; n < 4; n++) {
            acc_o[n][0] *= fac; acc_o[n][1] *= fac;
            acc_o[n][2] *= fac; acc_o[n][3] *= fac;
            u16x4 pk = { f2b(s[n][0]), f2b(s[n][1]), f2b(s[n][2]), f2b(s[n][3]) };
            *(u16x4*)(Pw + ((l15*128 + n*32 + lg*8) ^ swz)) = pk;
        }
        // PV: O^T += V^T(d rows) x P(q rows)
#pragma unroll
        for (int kk = 0; kk < 2; ++kk) {
            bf16x8 pa = *(const bf16x8*)(Pw + ((l15*128 + kk*64 + lg*16) ^ swz));
#pragma unroll
            for (int n = 0; n < 4; n++) {
                bf16x8 vb = *(const bf16x8*)(Vh + (size_t)(n*16 + l15) * T_ + k0 + kk*32 + lg*8);
                acc_o[n] = mfma16(vb, pa, acc_o[n]);
            }
        }
    }
    const float inv = 1.f / l_r;             // lane-local
    u16* Orow = Ob + ((size_t)(var * B_ + b) * T_ + qrow) * D_ + h * HD_;
#pragma unroll
    for (int n = 0; n < 4; n++) {
        u16x4 ov = { f2b(acc_o[n][0] * inv), f2b(acc_o[n][1] * inv),
                     f2b(acc_o[n][2] * inv), f2b(acc_o[n][3] * inv) };
        *(u16x4*)(Orow + n*16 + lg*4) = ov;
    }
}

extern "C" void kernel_launch(void* const* d_in, const int* in_sizes, int n_in,
                              void* d_out, int out_size, void* d_ws, size_t ws_size,
                              hipStream_t stream) {
    const float* x_in   = (const float*)d_in[0];
    const float* gamma  = (const float*)d_in[1];
    const float* beta   = (const float*)d_in[2];
    const float* wqkv_f = (const float*)d_in[3];
    const float* bqkv   = (const float*)d_in[4];
    const float* wout_f = (const float*)d_in[5];
    const float* bout   = (const float*)d_in[6];
    const unsigned char* smask = (const unsigned char*)d_in[7];
    float* out = (float*)d_out;

    char* ws = (char*)d_ws;
    u16* xb   = (u16*)(ws);                        // 8 MB  LN output, bf16 [4096][1024]
    u16* wqkv = (u16*)(ws + ((size_t)8  << 20));   // 6 MB  in_proj_w bf16
    u16* wo   = (u16*)(ws + ((size_t)14 << 20));   // 2 MB  out_w bf16
    u16* Qb   = (u16*)(ws + ((size_t)16 << 20));   // 8 MB  Q [b][h][t][d] (pre-scaled)
    u16* Kb   = (u16*)(ws + ((size_t)24 << 20));   // 8 MB  K [b][h][t][d]
    u16* Vt   = (u16*)(ws + ((size_t)32 << 20));   // 8 MB  V^T [b][h][d][t]
    u16* Ob   = (u16*)(ws + ((size_t)40 << 20));   // 16 MB O [2*4096][1024] bf16
    int* lens = (int*)(ws + ((size_t)56 << 20));   // 16 B  per-batch lengths

    len_kernel<<<dim3(B_), dim3(256), 0, stream>>>(smask, lens);
    cvt_bf16<<<dim3(1024), dim3(256), 0, stream>>>(wqkv_f, wqkv, (3 * D_ * D_) / 4);
    cvt_bf16<<<dim3(512),  dim3(256), 0, stream>>>(wout_f, wo, (D_ * D_) / 4);
    ln_kernel<<<dim3(B_ * T_), dim3(256), 0, stream>>>(x_in, gamma, beta, xb);
    gemm_bt<1><<<dim3(24, 32), dim3(256), 0, stream>>>(
        xb, wqkv, bqkv, nullptr, Qb, Kb, Vt, B_ * T_, 3 * D_, D_);
    attn_kernel<<<dim3(T_ / 64, B_ * H_, 2), dim3(256), 0, stream>>>(Qb, Kb, Vt, lens, Ob);
    gemm_bt<0><<<dim3(8, 64), dim3(256), 0, stream>>>(
        Ob, wo, bout, out, nullptr, nullptr, nullptr, 2 * B_ * T_, D_, D_);
}

// Round 4
// 201.710 us; speedup vs baseline: 1.4127x; 1.3686x over previous
//
#include <hip/hip_runtime.h>

#define B_ 4
#define T_ 1024
#define D_ 1024
#define H_ 16
#define HD_ 64

typedef unsigned short u16;
typedef __bf16 bf16x8 __attribute__((ext_vector_type(8)));
typedef float f32x4 __attribute__((ext_vector_type(4)));
typedef unsigned short u16x4 __attribute__((ext_vector_type(4)));

__device__ inline u16 f2b(float f) {
    union { float f; unsigned u; } v; v.f = f;
    unsigned r = v.u + 0x7fffu + ((v.u >> 16) & 1u);
    return (u16)(r >> 16);
}

__device__ inline f32x4 mfma16(bf16x8 a, bf16x8 b, f32x4 c) {
    return __builtin_amdgcn_mfma_f32_16x16x32_bf16(a, b, c, 0, 0, 0);
}

// ---------------- sequence lengths from mask (dtype-agnostic) ----------------
__global__ __launch_bounds__(256) void len_kernel(const unsigned char* __restrict__ m,
                                                  int* __restrict__ lens) {
    const int t = threadIdx.x;
    const int b = blockIdx.x;
    const int esz4 = (m[1] == 0);
    int c = 0;
    for (int i = t; i < T_; i += 256) {
        bool v = esz4 ? (((const int*)m)[b * T_ + i] != 0) : (m[b * T_ + i] != 0);
        c += v ? 1 : 0;
    }
#pragma unroll
    for (int off = 1; off < 64; off <<= 1) c += __shfl_xor(c, off);
    __shared__ int red[4];
    if ((t & 63) == 0) red[t >> 6] = c;
    __syncthreads();
    if (t == 0) lens[b] = red[0] + red[1] + red[2] + red[3];
}

// ---------------- fp32 -> bf16 conversion (weights) ----------------
__global__ __launch_bounds__(256) void cvt_bf16(const float* __restrict__ in,
                                                u16* __restrict__ out, int n4) {
    int i = blockIdx.x * 256 + threadIdx.x;
    int stride = gridDim.x * 256;
    for (; i < n4; i += stride) {
        float4 v = ((const float4*)in)[i];
        u16x4 o = { f2b(v.x), f2b(v.y), f2b(v.z), f2b(v.w) };
        ((u16x4*)out)[i] = o;
    }
}

// ---------------- LayerNorm -> bf16 x ----------------
__global__ __launch_bounds__(256) void ln_kernel(const float* __restrict__ x,
                                                 const float* __restrict__ g,
                                                 const float* __restrict__ be,
                                                 u16* __restrict__ y) {
    __shared__ float red[8];
    const int row = blockIdx.x;
    const int tid = threadIdx.x;
    const float* xr = x + (size_t)row * D_;
    float4 v = ((const float4*)xr)[tid];
    float s  = v.x + v.y + v.z + v.w;
    float ss = v.x*v.x + v.y*v.y + v.z*v.z + v.w*v.w;
#pragma unroll
    for (int off = 1; off < 64; off <<= 1) {
        s  += __shfl_xor(s, off);
        ss += __shfl_xor(ss, off);
    }
    const int w = tid >> 6;
    if ((tid & 63) == 0) { red[w*2] = s; red[w*2+1] = ss; }
    __syncthreads();
    s  = red[0] + red[2] + red[4] + red[6];
    ss = red[1] + red[3] + red[5] + red[7];
    const float mu = s * (1.f/1024.f);
    const float rs = rsqrtf(ss*(1.f/1024.f) - mu*mu + 1e-5f);
    float4 gv = ((const float4*)g)[tid];
    float4 bv = ((const float4*)be)[tid];
    u16x4 o = { f2b((v.x-mu)*rs*gv.x + bv.x),
                f2b((v.y-mu)*rs*gv.y + bv.y),
                f2b((v.z-mu)*rs*gv.z + bv.z),
                f2b((v.w-mu)*rs*gv.w + bv.w) };
    ((u16x4*)(y + (size_t)row * D_))[tid] = o;
}

// ---------------- GEMM C = A @ B^T (+bias), A:MxK, B:NxK, bf16 ----------------
template <int EPI>
__global__ __launch_bounds__(256) void gemm_bt(
    const u16* __restrict__ A, const u16* __restrict__ Bw,
    const float* __restrict__ bias, float* __restrict__ Cf,
    u16* __restrict__ Qb, u16* __restrict__ Kb, u16* __restrict__ Vt,
    int M, int N, int K) {
    __shared__ u16 As[128 * 64];
    __shared__ u16 Bs[128 * 64];
    const int tid = threadIdx.x;
    const int w = tid >> 6, l = tid & 63;
    const int l15 = l & 15, lg = l >> 4;
    const int m0 = blockIdx.y * 128, n0 = blockIdx.x * 128;
    const int wr = w >> 1, wc = w & 1;
    const int ldr = l >> 3;          // row within 8-row chunk
    const int ldc = (l & 7) * 8;     // bf16 column

    f32x4 acc[4][4];
#pragma unroll
    for (int m = 0; m < 4; m++)
#pragma unroll
        for (int n = 0; n < 4; n++) acc[m][n] = (f32x4){0.f, 0.f, 0.f, 0.f};

    for (int k0 = 0; k0 < K; k0 += 64) {
#pragma unroll
        for (int it = 0; it < 4; ++it) {
            const int c = it * 4 + w;
            const u16* ga = A  + (size_t)(m0 + c*8 + ldr) * K + (k0 + ldc);
            const u16* gb = Bw + (size_t)(n0 + c*8 + ldr) * K + (k0 + ldc);
            __builtin_amdgcn_global_load_lds(
                (const __attribute__((address_space(1))) unsigned int*)ga,
                (__attribute__((address_space(3))) unsigned int*)(As + c * 512), 16, 0, 0);
            __builtin_amdgcn_global_load_lds(
                (const __attribute__((address_space(1))) unsigned int*)gb,
                (__attribute__((address_space(3))) unsigned int*)(Bs + c * 512), 16, 0, 0);
        }
        __syncthreads();
#pragma unroll
        for (int kk = 0; kk < 64; kk += 32) {
            bf16x8 af[4], bfr[4];
#pragma unroll
            for (int m = 0; m < 4; m++)
                af[m] = *(const bf16x8*)&As[(wr*64 + m*16 + l15) * 64 + kk + lg*8];
#pragma unroll
            for (int n = 0; n < 4; n++)
                bfr[n] = *(const bf16x8*)&Bs[(wc*64 + n*16 + l15) * 64 + kk + lg*8];
#pragma unroll
            for (int m = 0; m < 4; m++)
#pragma unroll
                for (int n = 0; n < 4; n++)
                    acc[m][n] = mfma16(af[m], bfr[n], acc[m][n]);
        }
        __syncthreads();
    }

#pragma unroll
    for (int m = 0; m < 4; m++) {
#pragma unroll
        for (int n = 0; n < 4; n++) {
            const int col = n0 + wc*64 + n*16 + l15;
            const float bv = bias[col];
            if constexpr (EPI == 0) {
#pragma unroll
                for (int r = 0; r < 4; r++) {
                    const int row = m0 + wr*64 + m*16 + lg*4 + r;
                    Cf[(size_t)row * N + col] = acc[m][n][r] + bv;
                }
            } else {
                const int which = col >> 10;
                const int d = col & 1023;
                const int h = d >> 6, hd = d & 63;
#pragma unroll
                for (int r = 0; r < 4; r++) {
                    const int row = m0 + wr*64 + m*16 + lg*4 + r;
                    const int bb = row >> 10, t = row & 1023;
                    const float v = acc[m][n][r] + bv;
                    const size_t bh = (size_t)bb * H_ + h;
                    if (which == 0)      Qb[(bh * T_ + t) * HD_ + hd] = f2b(v * 0.125f);
                    else if (which == 1) Kb[(bh * T_ + t) * HD_ + hd] = f2b(v);
                    else                 Vt[(bh * HD_ + hd) * T_ + t] = f2b(v);
                }
            }
        }
    }
}

// ---------------- Merged dual-mask flash attention ----------------
// grid: (T/64, B*H). Both mask variants in one pass.
// Swapped QK^T (mfma(K,Q) -> S^T) keeps softmax lane-local.
// Online (causal) state shares the offline running max m1 (m1 >= online max,
// so P<=1 always). Below the diagonal tile both variants see identical masked
// scores => states are IDENTICAL until kt==qt: fork there (copy acc/l), apply
// the causal mask to the already-exp'd P, one extra bounce+PV. Tiles kt>qt
// touch only the offline state. Online pass costs ~1 extra tile per block.
// K is register-double-buffered (prefetch t+1 during t); V issued early.
__global__ __launch_bounds__(256) void attn_kernel(
    const u16* __restrict__ Qb, const u16* __restrict__ Kb,
    const u16* __restrict__ Vt, const int* __restrict__ lens,
    u16* __restrict__ Ob) {
    __shared__ char Pl[4][16 * 64 * 2];   // per-wave P bounce, XOR-swizzled
    const int qt  = blockIdx.x;
    const int bh  = blockIdx.y;
    const int b = bh >> 4, h = bh & 15;
    const int tid = threadIdx.x, w = tid >> 6, l = tid & 63;
    const int l15 = l & 15, lg = l >> 4;
    const int len = lens[b];

    const u16* Qh = Qb + (size_t)bh * (T_ * HD_);
    const u16* Kh = Kb + (size_t)bh * (T_ * HD_);
    const u16* Vh = Vt + (size_t)bh * (HD_ * T_);

    const int q0 = qt * 64 + w * 16;
    const int qrow = q0 + l15;              // this lane's q row

    const bf16x8 qf0 = *(const bf16x8*)(Qh + (size_t)qrow * HD_ + lg * 8);
    const bf16x8 qf1 = *(const bf16x8*)(Qh + (size_t)qrow * HD_ + 32 + lg * 8);

    f32x4 acc0[4], acc1[4];                 // O^T[d][q]: online / offline
#pragma unroll
    for (int n = 0; n < 4; n++) {
        acc0[n] = (f32x4){0.f, 0.f, 0.f, 0.f};
        acc1[n] = (f32x4){0.f, 0.f, 0.f, 0.f};
    }
    float m1 = -1e30f, l1 = 0.f, l0 = 0.f;

    const int ntk = (len + 63) >> 6;        // >= 8 since len >= T/2

    char* Pw = &Pl[w][0];
    const int swz = (l15 & 7) << 4;

    bf16x8 kfA[4][2], kfB[4][2];
    // prologue: K tile 0 -> kfA
#pragma unroll
    for (int n = 0; n < 4; n++) {
        const u16* kr = Kh + (size_t)(n*16 + l15) * HD_ + lg * 8;
        kfA[n][0] = *(const bf16x8*)kr;
        kfA[n][1] = *(const bf16x8*)(kr + 32);
    }

    int kt = 0;
    auto body = [&](bf16x8 (&kc)[4][2], bf16x8 (&kn)[4][2]) {
        const int k0 = kt * 64;
        // QK^T (consumes kc)
        f32x4 s[4];
#pragma unroll
        for (int n = 0; n < 4; n++) {
            f32x4 z = (f32x4){0.f, 0.f, 0.f, 0.f};
            z = mfma16(kc[n][0], qf0, z);
            z = mfma16(kc[n][1], qf1, z);
            s[n] = z;
        }
        // prefetch K(t+1) -> kn (clamped; harmless duplicate on last tile)
        const int ktn = (kt + 1 < ntk) ? kt + 1 : ntk - 1;
        const u16* Kn = Kh + (size_t)(ktn * 64 + l15) * HD_ + lg * 8;
#pragma unroll
        for (int n = 0; n < 4; n++) {
            kn[n][0] = *(const bf16x8*)(Kn + (size_t)(n*16) * HD_);
            kn[n][1] = *(const bf16x8*)(Kn + (size_t)(n*16) * HD_ + 32);
        }
        // V(t) early issue (consumed after the bounce)
        bf16x8 vf[4][2];
#pragma unroll
        for (int n = 0; n < 4; n++) {
            const u16* vr = Vh + (size_t)(n*16 + l15) * T_ + k0 + lg * 8;
            vf[n][0] = *(const bf16x8*)vr;
            vf[n][1] = *(const bf16x8*)(vr + 32);
        }
        // offline mask + lane-local max tree
        float mxn[4];
#pragma unroll
        for (int n = 0; n < 4; n++) {
            const int kb = k0 + n*16 + lg*4;
#pragma unroll
            for (int r = 0; r < 4; r++)
                if (kb + r >= len) s[n][r] = -1e30f;
            mxn[n] = fmaxf(fmaxf(s[n][0], s[n][1]), fmaxf(s[n][2], s[n][3]));
        }
        float mx = fmaxf(fmaxf(mxn[0], mxn[1]), fmaxf(mxn[2], mxn[3]));
        mx = fmaxf(mx, __shfl_xor(mx, 16));
        mx = fmaxf(mx, __shfl_xor(mx, 32));
        const float mnew = fmaxf(m1, mx);
        const float fac = __expf(m1 - mnew);
        m1 = mnew;
        // exp + lane-local sum tree
        float pn[4];
#pragma unroll
        for (int n = 0; n < 4; n++) {
            float e0 = __expf(s[n][0] - mnew);
            float e1 = __expf(s[n][1] - mnew);
            float e2 = __expf(s[n][2] - mnew);
            float e3 = __expf(s[n][3] - mnew);
            s[n][0] = e0; s[n][1] = e1; s[n][2] = e2; s[n][3] = e3;
            pn[n] = (e0 + e1) + (e2 + e3);
        }
        float ps = (pn[0] + pn[1]) + (pn[2] + pn[3]);
        ps += __shfl_xor(ps, 16);
        ps += __shfl_xor(ps, 32);

        const bool diag = (kt == qt);
        if (diag) l0 = l1 * fac;            // fork l BEFORE this tile's sum
        l1 = l1 * fac + ps;
#pragma unroll
        for (int n = 0; n < 4; n++) {
            acc1[n][0] *= fac; acc1[n][1] *= fac;
            acc1[n][2] *= fac; acc1[n][3] *= fac;
        }
        if (diag) {
#pragma unroll
            for (int n = 0; n < 4; n++) acc0[n] = acc1[n];  // fork acc pre-PV
        }
        // pack P1 -> LDS (swizzled), PV -> acc1
#pragma unroll
        for (int n = 0; n < 4; n++) {
            u16x4 pk = { f2b(s[n][0]), f2b(s[n][1]), f2b(s[n][2]), f2b(s[n][3]) };
            *(u16x4*)(Pw + ((l15*128 + n*32 + lg*8) ^ swz)) = pk;
        }
#pragma unroll
        for (int kk = 0; kk < 2; ++kk) {
            bf16x8 pa = *(const bf16x8*)(Pw + ((l15*128 + kk*64 + lg*16) ^ swz));
#pragma unroll
            for (int n = 0; n < 4; n++)
                acc0[n] = acc0[n]; // no-op placeholder removed by compiler
#pragma unroll
            for (int n = 0; n < 4; n++)
                acc1[n] = mfma16(vf[n][kk], pa, acc1[n]);
        }
        if (diag) {
            // P0 = causal-masked P1 (same exp reference m1)
            float pq[4];
#pragma unroll
            for (int n = 0; n < 4; n++) {
                const int kb = k0 + n*16 + lg*4;
                float e0 = (kb + 0 <= qrow) ? s[n][0] : 0.f;
                float e1 = (kb + 1 <= qrow) ? s[n][1] : 0.f;
                float e2 = (kb + 2 <= qrow) ? s[n][2] : 0.f;
                float e3 = (kb + 3 <= qrow) ? s[n][3] : 0.f;
                s[n][0] = e0; s[n][1] = e1; s[n][2] = e2; s[n][3] = e3;
                pq[n] = (e0 + e1) + (e2 + e3);
            }
            float ps0 = (pq[0] + pq[1]) + (pq[2] + pq[3]);
            ps0 += __shfl_xor(ps0, 16);
            ps0 += __shfl_xor(ps0, 32);
            l0 += ps0;
#pragma unroll
            for (int n = 0; n < 4; n++) {
                u16x4 pk = { f2b(s[n][0]), f2b(s[n][1]), f2b(s[n][2]), f2b(s[n][3]) };
                *(u16x4*)(Pw + ((l15*128 + n*32 + lg*8) ^ swz)) = pk;
            }
#pragma unroll
            for (int kk = 0; kk < 2; ++kk) {
                bf16x8 pa = *(const bf16x8*)(Pw + ((l15*128 + kk*64 + lg*16) ^ swz));
#pragma unroll
                for (int n = 0; n < 4; n++)
                    acc0[n] = mfma16(vf[n][kk], pa, acc0[n]);
            }
        }
    };

    while (true) {
        body(kfA, kfB); ++kt; if (kt >= ntk) break;
        body(kfB, kfA); ++kt; if (kt >= ntk) break;
    }

    if (qt >= ntk) {                        // diagonal never ran: online == offline
        l0 = l1;
#pragma unroll
        for (int n = 0; n < 4; n++) acc0[n] = acc1[n];
    }

    const float inv0 = 1.f / l0;
    const float inv1 = 1.f / l1;
    u16* O0 = Ob + ((size_t)b * T_ + qrow) * D_ + h * HD_;
    u16* O1 = O0 + (size_t)B_ * T_ * D_;
#pragma unroll
    for (int n = 0; n < 4; n++) {
        u16x4 o0 = { f2b(acc0[n][0] * inv0), f2b(acc0[n][1] * inv0),
                     f2b(acc0[n][2] * inv0), f2b(acc0[n][3] * inv0) };
        u16x4 o1 = { f2b(acc1[n][0] * inv1), f2b(acc1[n][1] * inv1),
                     f2b(acc1[n][2] * inv1), f2b(acc1[n][3] * inv1) };
        *(u16x4*)(O0 + n*16 + lg*4) = o0;
        *(u16x4*)(O1 + n*16 + lg*4) = o1;
    }
}

extern "C" void kernel_launch(void* const* d_in, const int* in_sizes, int n_in,
                              void* d_out, int out_size, void* d_ws, size_t ws_size,
                              hipStream_t stream) {
    const float* x_in   = (const float*)d_in[0];
    const float* gamma  = (const float*)d_in[1];
    const float* beta   = (const float*)d_in[2];
    const float* wqkv_f = (const float*)d_in[3];
    const float* bqkv   = (const float*)d_in[4];
    const float* wout_f = (const float*)d_in[5];
    const float* bout   = (const float*)d_in[6];
    const unsigned char* smask = (const unsigned char*)d_in[7];
    float* out = (float*)d_out;

    char* ws = (char*)d_ws;
    u16* xb   = (u16*)(ws);                        // 8 MB  LN output, bf16 [4096][1024]
    u16* wqkv = (u16*)(ws + ((size_t)8  << 20));   // 6 MB  in_proj_w bf16
    u16* wo   = (u16*)(ws + ((size_t)14 << 20));   // 2 MB  out_w bf16
    u16* Qb   = (u16*)(ws + ((size_t)16 << 20));   // 8 MB  Q [b][h][t][d] (pre-scaled)
    u16* Kb   = (u16*)(ws + ((size_t)24 << 20));   // 8 MB  K [b][h][t][d]
    u16* Vt   = (u16*)(ws + ((size_t)32 << 20));   // 8 MB  V^T [b][h][d][t]
    u16* Ob   = (u16*)(ws + ((size_t)40 << 20));   // 16 MB O [2*4096][1024] bf16
    int* lens = (int*)(ws + ((size_t)56 << 20));   // 16 B  per-batch lengths

    len_kernel<<<dim3(B_), dim3(256), 0, stream>>>(smask, lens);
    cvt_bf16<<<dim3(1024), dim3(256), 0, stream>>>(wqkv_f, wqkv, (3 * D_ * D_) / 4);
    cvt_bf16<<<dim3(512),  dim3(256), 0, stream>>>(wout_f, wo, (D_ * D_) / 4);
    ln_kernel<<<dim3(B_ * T_), dim3(256), 0, stream>>>(x_in, gamma, beta, xb);
    gemm_bt<1><<<dim3(24, 32), dim3(256), 0, stream>>>(
        xb, wqkv, bqkv, nullptr, Qb, Kb, Vt, B_ * T_, 3 * D_, D_);
    attn_kernel<<<dim3(T_ / 64, B_ * H_), dim3(256), 0, stream>>>(Qb, Kb, Vt, lens, Ob);
    gemm_bt<0><<<dim3(8, 64), dim3(256), 0, stream>>>(
        Ob, wo, bout, out, nullptr, nullptr, nullptr, 2 * B_ * T_, D_, D_);
}